// Round 12
// baseline (418.675 us; speedup 1.0000x reference)
//
#include <hip/hip_runtime.h>
#include <hip/hip_bf16.h>

// Problem constants
#define BB 8
#define CC 64
#define OO 128
#define HH 128
#define WW 128
#define HW (HH*WW)         // 16384
#define NTAP 9

typedef float f32x4 __attribute__((ext_vector_type(4)));
typedef short short8 __attribute__((ext_vector_type(8)));

__device__ __forceinline__ uint f2bf(float v) {
    uint b = __float_as_uint(v);
    return (b + 0x7FFFu + ((b >> 16) & 1u)) >> 16;   // RNE to bf16
}

__device__ __forceinline__ float sampf(const float* __restrict__ xc, int iy, int ix) {
    // padded-image coords (130x130, zero border of width 1)
    unsigned uy = (unsigned)(iy - 1), ux = (unsigned)(ix - 1);
    return (uy < 128u && ux < 128u) ? xc[uy * 128 + ux] : 0.f;
}

// ---------------------------------------------------------------------------
// Kernel 0: repack weights (validated verbatim).
// ---------------------------------------------------------------------------
__global__ void k_repack(const float* __restrict__ pw, const float* __restrict__ dw,
                         const float* __restrict__ cw,
                         float* __restrict__ wp1, float* __restrict__ wpd,
                         ushort* __restrict__ wb2) {
    int i = blockIdx.x * 256 + threadIdx.x;
    if (i < 10368) {
        int o = i % 18, t = (i / 18) % 9, c = i / 162;
        wp1[i] = pw[(o * 64 + c) * 9 + t];
    }
    if (i < 36864) {
        int o = i % 64, t = (i / 64) % 9, c = i / 576;
        wpd[i] = dw[(o * 64 + c) * 9 + t];
    }
    if (i < 73728) {
        int j = i & 7, lane = (i >> 3) & 63, ot = (i >> 9) & 7;
        int kc = (i >> 12) & 1, t = i >> 13;
        int c = kc * 32 + (lane >> 4) * 8 + j;
        int oc = ot * 16 + (lane & 15);
        wb2[i] = (ushort)f2bf(cw[(oc * 64 + c) * 9 + t]);
    }
}

// ---------------------------------------------------------------------------
// Kernel 1: p_conv — 3x3 conv, 64 -> 18 channels, pad 1 (validated).
// ---------------------------------------------------------------------------
__global__ __launch_bounds__(256) void k_pconv(const float* __restrict__ x,
                                               const float* __restrict__ wp1,
                                               const float* __restrict__ pb,
                                               float* __restrict__ off) {
    int tile = blockIdx.x;
    int b = blockIdx.y;
    int ty0 = (tile / 8) * 16, tx0 = (tile % 8) * 16;
    int tid = threadIdx.x;
    int py = tid / 16, px = tid % 16;
    __shared__ float lx[16][18 * 18];

    float acc[18];
#pragma unroll
    for (int o = 0; o < 18; o++) acc[o] = pb[o];

    for (int cc = 0; cc < 4; cc++) {
        __syncthreads();
        for (int idx = tid; idx < 16 * 324; idx += 256) {
            int c = idx / 324, r = (idx % 324) / 18, col = idx % 18;
            int gy = ty0 + r - 1, gx = tx0 + col - 1;
            float v = 0.f;
            if ((unsigned)gy < 128u && (unsigned)gx < 128u)
                v = x[((b * 64 + cc * 16 + c) * 128 + gy) * 128 + gx];
            lx[c][r * 18 + col] = v;
        }
        __syncthreads();
        for (int c = 0; c < 16; c++) {
#pragma unroll
            for (int t = 0; t < 9; t++) {
                float xv = lx[c][(py + t / 3) * 18 + px + t % 3];
                const float* wr = wp1 + ((cc * 16 + c) * 9 + t) * 18;
#pragma unroll
                for (int o = 0; o < 18; o++) acc[o] = fmaf(xv, wr[o], acc[o]);
            }
        }
    }
    int yy = ty0 + py, xx = tx0 + px;
#pragma unroll
    for (int o = 0; o < 18; o++)
        off[((b * 18 + o) * 128 + yy) * 128 + xx] = acc[o];
}

// ---------------------------------------------------------------------------
// Kernel 2: deformable conv fp32 — R11 structure + LDS-instruction reduction:
//  * 2x2-contiguous fast path: mwin16[e] stores o00 only (0xFFFF = fallback);
//    gather reads pairs (o00,o00+1), (o00+16,o00+17) -> ds_read2_b32 merge
//    (2 LDS reads/tap instead of 4).
//  * double-buffered xtile: stage(cc+1) joins the gather phase (other
//    buffer) -> 2 barriers/chunk instead of 3.
// LDS = 1280 + 9216 + 8192 + 9280 = 27968 B -> 5 blocks/CU.
// Hazards: gather(cc) reads xt[cur]+meta, writes xo; stage writes xt[cur^1]
// (disjoint) | SYNC | contract reads xo | SYNC | next gather.
// ---------------------------------------------------------------------------
__global__ __launch_bounds__(256) void k_deform(const float* __restrict__ x,
                                                const float* __restrict__ off,
                                                const float* __restrict__ wpd,
                                                float* __restrict__ y) {
    int tile = blockIdx.x;                 // 0..255
    int b = blockIdx.y;
    int ty0 = (tile / 16) * 8, tx0 = (tile % 16) * 8;
    int tid = threadIdx.x;

    __shared__ ushort mwin16[640];         // o00 per tap; 0xFFFF = fallback (576 used)
    __shared__ float4 mwt[576];            // bilinear weights (OOB corners zeroed)
    __shared__ float  xtile[2][4 * 256];   // double-buffered 16x16 window x 4 ch
    __shared__ float  xo[4][580];

    // ---- Stage A: bilinear metadata (R2/R9-proven math + fast-path flag) ----
    for (int e = tid; e < 576; e += 256) {
        int n = e >> 6, p = e & 63;
        int py = p >> 3, px = p & 7;
        int yy = ty0 + py, xx = tx0 + px;
        float offh = off[((b * 18 + n) * 128 + yy) * 128 + xx];
        float offw = off[((b * 18 + 9 + n) * 128 + yy) * 128 + xx];
        float ph = (float)(yy + 1) + (float)(n / 3 - 1) + offh;
        float pw = (float)(xx + 1) + (float)(n % 3 - 1) + offw;
        ph = fminf(fmaxf(ph, 0.f), 129.f);
        pw = fminf(fmaxf(pw, 0.f), 129.f);
        float fh = floorf(ph), fw = floorf(pw);
        int lth = (int)fh, ltw = (int)fw;
        int rbh = min(lth + 1, 129), rbw = min(ltw + 1, 129);
        float dh_l = 1.f + (fh - ph);
        float dh_r = 1.f - ((float)rbh - ph);
        float dw_l = 1.f + (fw - pw);
        float dw_r = 1.f - ((float)rbw - pw);
        int uy0 = lth - 1, ux0 = ltw - 1, uy1 = rbh - 1, ux1 = rbw - 1;
        bool iy0 = (unsigned)uy0 < 128u, ix0 = (unsigned)ux0 < 128u;
        bool iy1 = (unsigned)uy1 < 128u, ix1 = (unsigned)ux1 < 128u;
        float w_lt = (iy0 && ix0) ? dh_l * dw_l : 0.f;
        float w_rb = (iy1 && ix1) ? dh_r * dw_r : 0.f;
        float w_lb = (iy0 && ix1) ? dh_l * dw_r : 0.f;
        float w_rt = (iy1 && ix0) ? dh_r * dw_l : 0.f;
        mwt[e] = make_float4(w_lt, w_rb, w_lb, w_rt);
        int wy0 = uy0 - ty0 + 4, wx0 = ux0 - tx0 + 4;
        // fast path: unclamped 2x2 footprint fully inside the 16x16 window
        ushort w16 = 0xFFFFu;
        if (rbh == lth + 1 && rbw == ltw + 1 &&
            (unsigned)wy0 < 15u && (unsigned)wx0 < 15u) {
            w16 = (ushort)(wy0 * 16 + wx0);
        }
        mwin16[e] = w16;
    }

    // ---- prologue: stage chunk 0 into buffer 0 ----
#pragma unroll
    for (int i2 = 0; i2 < 4; i2++) {
        int idx = tid + 256 * i2;          // 0..1023
        int c = idx >> 8, wp = idx & 255;
        int gy = ty0 - 4 + (wp >> 4), gx = tx0 - 4 + (wp & 15);
        float v = 0.f;
        if ((unsigned)gy < 128u && (unsigned)gx < 128u)
            v = x[(size_t)(b * 64 + c) * HW + gy * 128 + gx];
        xtile[0][idx] = v;
    }
    __syncthreads();                       // metadata + xtile(0) ready

    float acc[4][4] = {};
    int pq = tid / 16;                     // pixel quad 0..15
    int oq = tid % 16;                     // oc quad   0..15
    int cg = tid >> 6;                     // gather channel 0..3 (one per wave)
    int l64 = tid & 63;
    int cgoff = cg * 256;
    int cur = 0;

    for (int cc = 0; cc < 16; cc++) {
        // ---- gather from LDS window (fast: 2 paired reads per tap) ----
        const float* xt = &xtile[cur][cgoff];
#pragma unroll 2
        for (int i = 0; i < 9; i++) {
            int e = l64 + 64 * i;
            ushort w16 = mwin16[e];
            float4 g = mwt[e];
            float v;
            if (__builtin_expect(w16 != 0xFFFFu, 1)) {
                const float* bp = xt + w16;
                float a00 = bp[0];
                float a01 = bp[1];
                float a10 = bp[16];
                float a11 = bp[17];
                v = g.x * a00 + g.z * a01 + g.w * a10 + g.y * a11;
            } else {
                // cold fallback: exact R2 global path (weights reused from mwt)
                int n = e >> 6, p = e & 63;
                int yy2 = ty0 + (p >> 3), xx2 = tx0 + (p & 7);
                float offh = off[((b * 18 + n) * 128 + yy2) * 128 + xx2];
                float offw = off[((b * 18 + 9 + n) * 128 + yy2) * 128 + xx2];
                float ph = fminf(fmaxf((float)(yy2 + 1) + (float)(n / 3 - 1) + offh, 0.f), 129.f);
                float pw = fminf(fmaxf((float)(xx2 + 1) + (float)(n % 3 - 1) + offw, 0.f), 129.f);
                int lth = (int)floorf(ph), ltw = (int)floorf(pw);
                int rbh = min(lth + 1, 129), rbw = min(ltw + 1, 129);
                const float* xc = x + (size_t)(b * 64 + cc * 4 + cg) * HW;
                v = g.x * sampf(xc, lth, ltw) + g.y * sampf(xc, rbh, rbw)
                  + g.z * sampf(xc, lth, rbw) + g.w * sampf(xc, rbh, ltw);
            }
            xo[cg][e] = v;
        }
        // ---- stage next chunk into the OTHER buffer (same phase, no hazard) ----
        if (cc < 15) {
            float* xtn = xtile[cur ^ 1];
#pragma unroll
            for (int i2 = 0; i2 < 4; i2++) {
                int idx = tid + 256 * i2;
                int c = idx >> 8, wp = idx & 255;
                int gy = ty0 - 4 + (wp >> 4), gx = tx0 - 4 + (wp & 15);
                float v = 0.f;
                if ((unsigned)gy < 128u && (unsigned)gx < 128u)
                    v = x[(size_t)(b * 64 + (cc + 1) * 4 + c) * HW + gy * 128 + gx];
                xtn[idx] = v;
            }
        }
        __syncthreads();                   // xo ready; next xtile staged
        // ---- contraction (R2/R8-proven inner body) ----
        for (int c = 0; c < 4; c++) {
#pragma unroll
            for (int n = 0; n < 9; n++) {
                float4 xv = *(const float4*)&xo[c][n * 64 + pq * 4];
                const float4 wv = *(const float4*)(wpd + (((cc * 4 + c) * 9 + n) * 64) + oq * 4);
                acc[0][0] = fmaf(xv.x, wv.x, acc[0][0]);
                acc[0][1] = fmaf(xv.x, wv.y, acc[0][1]);
                acc[0][2] = fmaf(xv.x, wv.z, acc[0][2]);
                acc[0][3] = fmaf(xv.x, wv.w, acc[0][3]);
                acc[1][0] = fmaf(xv.y, wv.x, acc[1][0]);
                acc[1][1] = fmaf(xv.y, wv.y, acc[1][1]);
                acc[1][2] = fmaf(xv.y, wv.z, acc[1][2]);
                acc[1][3] = fmaf(xv.y, wv.w, acc[1][3]);
                acc[2][0] = fmaf(xv.z, wv.x, acc[2][0]);
                acc[2][1] = fmaf(xv.z, wv.y, acc[2][1]);
                acc[2][2] = fmaf(xv.z, wv.z, acc[2][2]);
                acc[2][3] = fmaf(xv.z, wv.w, acc[2][3]);
                acc[3][0] = fmaf(xv.w, wv.x, acc[3][0]);
                acc[3][1] = fmaf(xv.w, wv.y, acc[3][1]);
                acc[3][2] = fmaf(xv.w, wv.z, acc[3][2]);
                acc[3][3] = fmaf(xv.w, wv.w, acc[3][3]);
            }
        }
        __syncthreads();                   // contraction done; xo/xt[cur] reusable
        cur ^= 1;
    }

#pragma unroll
    for (int i = 0; i < 4; i++) {
        int p = pq * 4 + i;
        int yy = ty0 + p / 8, xx = tx0 + p % 8;
#pragma unroll
        for (int j = 0; j < 4; j++) {
            int o = oq * 4 + j;
            y[((b * 64 + o) * 128 + yy) * 128 + xx] = acc[i][j];
        }
    }
}

// ---------------------------------------------------------------------------
// Kernel 3a/3b: BN statistics, two-stage (validated).
// ---------------------------------------------------------------------------
__global__ __launch_bounds__(256) void k_bnpart(const float* __restrict__ y,
                                                float* __restrict__ part) {
    int c = blockIdx.x, b = blockIdx.y;
    int tid = threadIdx.x;
    const float4* p = (const float4*)(y + (size_t)(b * 64 + c) * HW);
    float s = 0.f, sq = 0.f;
    for (int i = tid; i < HW / 4; i += 256) {
        float4 v = p[i];
        s += v.x + v.y + v.z + v.w;
        sq += v.x * v.x + v.y * v.y + v.z * v.z + v.w * v.w;
    }
#pragma unroll
    for (int o = 32; o > 0; o >>= 1) {
        s += __shfl_down(s, o);
        sq += __shfl_down(sq, o);
    }
    __shared__ float rs[4], rq[4];
    int wid = tid >> 6;
    if ((tid & 63) == 0) { rs[wid] = s; rq[wid] = sq; }
    __syncthreads();
    if (tid == 0) {
        part[(b * 64 + c) * 2]     = rs[0] + rs[1] + rs[2] + rs[3];
        part[(b * 64 + c) * 2 + 1] = rq[0] + rq[1] + rq[2] + rq[3];
    }
}

__global__ void k_bnfinal(const float* __restrict__ part,
                          const float* __restrict__ gamma,
                          const float* __restrict__ beta,
                          float* __restrict__ ss) {
    int c = threadIdx.x;                   // 64 threads
    float s = 0.f, sq = 0.f;
#pragma unroll
    for (int b = 0; b < 8; b++) {
        s += part[(b * 64 + c) * 2];
        sq += part[(b * 64 + c) * 2 + 1];
    }
    const float inv = 1.f / (float)(8 * HW);
    float mean = s * inv;
    float var = sq * inv - mean * mean;
    float scale = gamma[c] * rsqrtf(var + 1e-5f);
    ss[c] = scale;
    ss[64 + c] = beta[c] - mean * scale;
}

// ---------------------------------------------------------------------------
// Kernel 4: conv2 via MFMA — validated verbatim.
// ---------------------------------------------------------------------------
__global__ __launch_bounds__(256) void k_conv2(const float* __restrict__ x,
                                               const float* __restrict__ y,
                                               const float* __restrict__ ss,
                                               const ushort* __restrict__ wb2,
                                               const float* __restrict__ b2,
                                               float* __restrict__ out) {
    int tile = blockIdx.x, b = blockIdx.y;
    int ty0 = (tile / 16) * 8, tx0 = (tile % 16) * 8;
    int tid = threadIdx.x;

    __shared__ uint lz[3600];              // [100 pos][36 dwords] bf16 c-pairs

    for (int idx = tid; idx < 3200; idx += 256) {
        int q = idx / 100, pos = idx % 100;
        int r = pos / 10, col = pos % 10;
        int gy = ty0 + r - 1, gx = tx0 + col - 1;
        uint u = 0;
        if ((unsigned)gy < 128u && (unsigned)gx < 128u) {
            int c0 = q * 2;
            int gi = ((b * 64 + c0) * HW) + gy * 128 + gx;
            float t0 = fmaf(y[gi], ss[c0], ss[64 + c0]);
            float v0 = fmaxf(t0, 0.f) + x[gi];
            float t1 = fmaf(y[gi + HW], ss[c0 + 1], ss[65 + c0]);
            float v1 = fmaxf(t1, 0.f) + x[gi + HW];
            u = (f2bf(v1) << 16) | f2bf(v0);
        }
        lz[pos * 36 + q] = u;
    }
    __syncthreads();

    int lane = tid & 63, pg = tid >> 6;
    int r16 = lane & 15, jg = lane >> 4;
    int p = pg * 16 + r16;
    int pyA = p >> 3, pxA = p & 7;

    f32x4 acc[8];
#pragma unroll
    for (int ot = 0; ot < 8; ot++) {
        float bv = b2[ot * 16 + r16];
        acc[ot] = (f32x4){bv, bv, bv, bv};
    }

#pragma unroll
    for (int t = 0; t < 9; t++) {
        int pos = (pyA + t / 3) * 10 + (pxA + t % 3);
#pragma unroll
        for (int kc = 0; kc < 2; kc++) {
            short8 av = *(const short8*)(lz + pos * 36 + kc * 16 + jg * 4);
            const ushort* wk = wb2 + (t * 2 + kc) * 4096 + lane * 8;
#pragma unroll
            for (int ot = 0; ot < 8; ot++) {
                short8 bv = *(const short8*)(wk + ot * 512);
                acc[ot] = __builtin_amdgcn_mfma_f32_16x16x32_bf16(av, bv, acc[ot], 0, 0, 0);
            }
        }
    }

    // ---- epilogue: direct per-lane vector stores ----
    int p0 = pg * 16 + jg * 4;
    int yy = ty0 + (p0 >> 3), xx = tx0 + (p0 & 7);
#pragma unroll
    for (int ot = 0; ot < 8; ot++) {
        int oc = ot * 16 + r16;
        *(f32x4*)(out + (size_t)(b * 128 + oc) * HW + yy * 128 + xx) = acc[ot];
    }
}

// ---------------------------------------------------------------------------
extern "C" void kernel_launch(void* const* d_in, const int* in_sizes, int n_in,
                              void* d_out, int out_size, void* d_ws, size_t ws_size,
                              hipStream_t stream) {
    const float* x     = (const float*)d_in[0];
    const float* pw    = (const float*)d_in[1];
    const float* pb    = (const float*)d_in[2];
    const float* dw    = (const float*)d_in[3];
    const float* gamma = (const float*)d_in[4];
    const float* beta  = (const float*)d_in[5];
    const float* cw    = (const float*)d_in[6];
    const float* cb    = (const float*)d_in[7];
    float* out = (float*)d_out;
    float* ws  = (float*)d_ws;

    // workspace layout (float offsets)
    float*  wp1  = ws;                      // 10368
    float*  ss   = ws + 10368;              // 128
    float*  part = ws + 10496;              // 1024
    float*  wpd  = ws + 11520;              // 36864 -> ends 48384
    ushort* wb2  = (ushort*)(ws + 48384);   // 73728 sh (36864 f) -> ends 85248
    float*  off  = ws + 85248;              // 2359296 -> ends 2444544
    float*  yb   = ws + 2444544;            // 8388608 -> ends 10833152
    // total: 10833152 floats = 43.3 MB

    k_repack<<<dim3(288), dim3(256), 0, stream>>>(pw, dw, cw, wp1, wpd, wb2);
    k_pconv<<<dim3(64, 8), dim3(256), 0, stream>>>(x, wp1, pb, off);
    k_deform<<<dim3(256, 8), dim3(256), 0, stream>>>(x, off, wpd, yb);
    k_bnpart<<<dim3(64, 8), dim3(256), 0, stream>>>(yb, part);
    k_bnfinal<<<dim3(1), dim3(64), 0, stream>>>(part, gamma, beta, ss);
    k_conv2<<<dim3(256, 8), dim3(256), 0, stream>>>(x, yb, ss, wb2, cb, out);
}

// Round 13
// 369.629 us; speedup vs baseline: 1.1327x; 1.1327x over previous
//
#include <hip/hip_runtime.h>
#include <hip/hip_bf16.h>

// Problem constants
#define BB 8
#define CC 64
#define OO 128
#define HH 128
#define WW 128
#define HW (HH*WW)         // 16384
#define NTAP 9

typedef float f32x4 __attribute__((ext_vector_type(4)));
typedef short short8 __attribute__((ext_vector_type(8)));

__device__ __forceinline__ uint f2bf(float v) {
    uint b = __float_as_uint(v);
    return (b + 0x7FFFu + ((b >> 16) & 1u)) >> 16;   // RNE to bf16
}

__device__ __forceinline__ float sampf(const float* __restrict__ xc, int iy, int ix) {
    // padded-image coords (130x130, zero border of width 1)
    unsigned uy = (unsigned)(iy - 1), ux = (unsigned)(ix - 1);
    return (uy < 128u && ux < 128u) ? xc[uy * 128 + ux] : 0.f;
}

// ---------------------------------------------------------------------------
// Kernel 0: repack weights (validated verbatim).
// ---------------------------------------------------------------------------
__global__ void k_repack(const float* __restrict__ pw, const float* __restrict__ dw,
                         const float* __restrict__ cw,
                         float* __restrict__ wp1, float* __restrict__ wpd,
                         ushort* __restrict__ wb2) {
    int i = blockIdx.x * 256 + threadIdx.x;
    if (i < 10368) {
        int o = i % 18, t = (i / 18) % 9, c = i / 162;
        wp1[i] = pw[(o * 64 + c) * 9 + t];
    }
    if (i < 36864) {
        int o = i % 64, t = (i / 64) % 9, c = i / 576;
        wpd[i] = dw[(o * 64 + c) * 9 + t];
    }
    if (i < 73728) {
        int j = i & 7, lane = (i >> 3) & 63, ot = (i >> 9) & 7;
        int kc = (i >> 12) & 1, t = i >> 13;
        int c = kc * 32 + (lane >> 4) * 8 + j;
        int oc = ot * 16 + (lane & 15);
        wb2[i] = (ushort)f2bf(cw[(oc * 64 + c) * 9 + t]);
    }
}

// ---------------------------------------------------------------------------
// Kernel 1: p_conv — 3x3 conv, 64 -> 18 channels, pad 1 (validated).
// ---------------------------------------------------------------------------
__global__ __launch_bounds__(256) void k_pconv(const float* __restrict__ x,
                                               const float* __restrict__ wp1,
                                               const float* __restrict__ pb,
                                               float* __restrict__ off) {
    int tile = blockIdx.x;
    int b = blockIdx.y;
    int ty0 = (tile / 8) * 16, tx0 = (tile % 8) * 16;
    int tid = threadIdx.x;
    int py = tid / 16, px = tid % 16;
    __shared__ float lx[16][18 * 18];

    float acc[18];
#pragma unroll
    for (int o = 0; o < 18; o++) acc[o] = pb[o];

    for (int cc = 0; cc < 4; cc++) {
        __syncthreads();
        for (int idx = tid; idx < 16 * 324; idx += 256) {
            int c = idx / 324, r = (idx % 324) / 18, col = idx % 18;
            int gy = ty0 + r - 1, gx = tx0 + col - 1;
            float v = 0.f;
            if ((unsigned)gy < 128u && (unsigned)gx < 128u)
                v = x[((b * 64 + cc * 16 + c) * 128 + gy) * 128 + gx];
            lx[c][r * 18 + col] = v;
        }
        __syncthreads();
        for (int c = 0; c < 16; c++) {
#pragma unroll
            for (int t = 0; t < 9; t++) {
                float xv = lx[c][(py + t / 3) * 18 + px + t % 3];
                const float* wr = wp1 + ((cc * 16 + c) * 9 + t) * 18;
#pragma unroll
                for (int o = 0; o < 18; o++) acc[o] = fmaf(xv, wr[o], acc[o]);
            }
        }
    }
    int yy = ty0 + py, xx = tx0 + px;
#pragma unroll
    for (int o = 0; o < 18; o++)
        off[((b * 18 + o) * 128 + yy) * 128 + xx] = acc[o];
}

// ---------------------------------------------------------------------------
// Kernel 2: deformable conv fp32 — R11 gather/stage structure verbatim;
// contraction restructured to lane-per-pixel + wave-uniform scalar weights:
//   wave w owns oc [w*16, w*16+16); lane = pixel; per k: ONE b32 LDS read
//   (xo[c][n*64+lane], conflict-free) + s_load weight row + 16 FMA.
// Cuts contraction LDS from 36xb128 (432 cyc) to 36xb32 (209 cyc) per
// wave-chunk and removes all wpd vector-VMEM traffic (scalar cache).
// LDS = 2304 + 9216 + 4096 + 9280 = 24896 B -> 6 blocks/CU.
// ---------------------------------------------------------------------------
__global__ __launch_bounds__(256) void k_deform(const float* __restrict__ x,
                                                const float* __restrict__ off,
                                                const float* __restrict__ wpd,
                                                float* __restrict__ y) {
    int tile = blockIdx.x;                 // 0..255
    int b = blockIdx.y;
    int ty0 = (tile / 16) * 8, tx0 = (tile % 16) * 8;
    int tid = threadIdx.x;

    __shared__ uint   mwin[576];           // packed window offsets; 0xFFFFFFFF = fallback
    __shared__ float4 mwt[576];            // bilinear weights (OOB corners zeroed)
    __shared__ float  xtile[4 * 256];      // [c][wy*16+wx], window = tile +/- 4
    __shared__ float  xo[4][580];

    // ---- Stage A: bilinear metadata (R2/R9/R11-proven math) ----
    for (int e = tid; e < 576; e += 256) {
        int n = e >> 6, p = e & 63;
        int py = p >> 3, px = p & 7;
        int yy = ty0 + py, xx = tx0 + px;
        float offh = off[((b * 18 + n) * 128 + yy) * 128 + xx];
        float offw = off[((b * 18 + 9 + n) * 128 + yy) * 128 + xx];
        float ph = (float)(yy + 1) + (float)(n / 3 - 1) + offh;
        float pw = (float)(xx + 1) + (float)(n % 3 - 1) + offw;
        ph = fminf(fmaxf(ph, 0.f), 129.f);
        pw = fminf(fmaxf(pw, 0.f), 129.f);
        float fh = floorf(ph), fw = floorf(pw);
        int lth = (int)fh, ltw = (int)fw;
        int rbh = min(lth + 1, 129), rbw = min(ltw + 1, 129);
        float dh_l = 1.f + (fh - ph);
        float dh_r = 1.f - ((float)rbh - ph);
        float dw_l = 1.f + (fw - pw);
        float dw_r = 1.f - ((float)rbw - pw);
        int uy0 = lth - 1, ux0 = ltw - 1, uy1 = rbh - 1, ux1 = rbw - 1;
        bool iy0 = (unsigned)uy0 < 128u, ix0 = (unsigned)ux0 < 128u;
        bool iy1 = (unsigned)uy1 < 128u, ix1 = (unsigned)ux1 < 128u;
        float w_lt = (iy0 && ix0) ? dh_l * dw_l : 0.f;
        float w_rb = (iy1 && ix1) ? dh_r * dw_r : 0.f;
        float w_lb = (iy0 && ix1) ? dh_l * dw_r : 0.f;
        float w_rt = (iy1 && ix0) ? dh_r * dw_l : 0.f;
        mwt[e] = make_float4(w_lt, w_rb, w_lb, w_rt);
        int wy0 = uy0 - ty0 + 4, wx0 = ux0 - tx0 + 4;
        int wy1 = uy1 - ty0 + 4, wx1 = ux1 - tx0 + 4;
        uint win = 0xFFFFFFFFu;
        if ((unsigned)wy0 < 16u && (unsigned)wx0 < 16u &&
            (unsigned)wy1 < 16u && (unsigned)wx1 < 16u) {
            uint o00 = (uint)(wy0 * 16 + wx0);
            uint o11 = (uint)(wy1 * 16 + wx1);
            uint o01 = (uint)(wy0 * 16 + wx1);
            uint o10 = (uint)(wy1 * 16 + wx0);
            win = o00 | (o11 << 8) | (o01 << 16) | (o10 << 24);
        }
        mwin[e] = win;
    }

    float acc[16] = {};
    int cg = tid >> 6;                     // gather channel / wave id 0..3
    int l64 = tid & 63;                    // lane = pixel in contraction
    int cgoff = cg * 256;
    int ob = __builtin_amdgcn_readfirstlane(cg * 16);  // wave's oc base

    for (int cc = 0; cc < 16; cc++) {
        // ---- stage 16x16 x-window for this 4-channel chunk (coalesced) ----
#pragma unroll
        for (int i2 = 0; i2 < 4; i2++) {
            int idx = tid + 256 * i2;      // 0..1023
            int c = idx >> 8, wp = idx & 255;
            int gy = ty0 - 4 + (wp >> 4), gx = tx0 - 4 + (wp & 15);
            float v = 0.f;
            if ((unsigned)gy < 128u && (unsigned)gx < 128u)
                v = x[(size_t)(b * 64 + cc * 4 + c) * HW + gy * 128 + gx];
            xtile[idx] = v;
        }
        __syncthreads();                   // xtile staged (prev phases closed)
        // ---- gather from LDS window (R11 code shape, unroll 2) ----
#pragma unroll 2
        for (int i = 0; i < 9; i++) {
            int e = l64 + 64 * i;
            uint w = mwin[e];
            float4 g = mwt[e];
            float v;
            if (__builtin_expect(w != 0xFFFFFFFFu, 1)) {
                float a00 = xtile[cgoff + (w & 255u)];
                float a11 = xtile[cgoff + ((w >> 8) & 255u)];
                float a01 = xtile[cgoff + ((w >> 16) & 255u)];
                float a10 = xtile[cgoff + (w >> 24)];
                v = g.x * a00 + g.y * a11 + g.z * a01 + g.w * a10;
            } else {
                // cold fallback: exact R2 global path (weights reused from mwt)
                int n = e >> 6, p = e & 63;
                int yy2 = ty0 + (p >> 3), xx2 = tx0 + (p & 7);
                float offh = off[((b * 18 + n) * 128 + yy2) * 128 + xx2];
                float offw = off[((b * 18 + 9 + n) * 128 + yy2) * 128 + xx2];
                float ph = fminf(fmaxf((float)(yy2 + 1) + (float)(n / 3 - 1) + offh, 0.f), 129.f);
                float pw = fminf(fmaxf((float)(xx2 + 1) + (float)(n % 3 - 1) + offw, 0.f), 129.f);
                int lth = (int)floorf(ph), ltw = (int)floorf(pw);
                int rbh = min(lth + 1, 129), rbw = min(ltw + 1, 129);
                const float* xc = x + (size_t)(b * 64 + cc * 4 + cg) * HW;
                v = g.x * sampf(xc, lth, ltw) + g.y * sampf(xc, rbh, rbw)
                  + g.z * sampf(xc, lth, rbw) + g.w * sampf(xc, rbh, ltw);
            }
            xo[cg][e] = v;
        }
        __syncthreads();                   // xo ready
        // ---- contraction: lane=pixel, wave-uniform weight rows (s_load) ----
        for (int c = 0; c < 4; c++) {
#pragma unroll
            for (int n = 0; n < 9; n++) {
                float xv = xo[c][n * 64 + l64];
                const float* wrow = wpd + (((cc * 4 + c) * 9 + n) * 64) + ob;
#pragma unroll
                for (int j = 0; j < 16; j++)
                    acc[j] = fmaf(xv, wrow[j], acc[j]);
            }
        }
        __syncthreads();                   // contraction done before next stage
    }

    // ---- epilogue: direct per-lane stores (lane=pixel, wave's 16 oc) ----
    int yy = ty0 + (l64 >> 3), xx = tx0 + (l64 & 7);
#pragma unroll
    for (int j = 0; j < 16; j++)
        y[(size_t)(b * 64 + ob + j) * HW + yy * 128 + xx] = acc[j];
}

// ---------------------------------------------------------------------------
// Kernel 3a/3b: BN statistics, two-stage (validated).
// ---------------------------------------------------------------------------
__global__ __launch_bounds__(256) void k_bnpart(const float* __restrict__ y,
                                                float* __restrict__ part) {
    int c = blockIdx.x, b = blockIdx.y;
    int tid = threadIdx.x;
    const float4* p = (const float4*)(y + (size_t)(b * 64 + c) * HW);
    float s = 0.f, sq = 0.f;
    for (int i = tid; i < HW / 4; i += 256) {
        float4 v = p[i];
        s += v.x + v.y + v.z + v.w;
        sq += v.x * v.x + v.y * v.y + v.z * v.z + v.w * v.w;
    }
#pragma unroll
    for (int o = 32; o > 0; o >>= 1) {
        s += __shfl_down(s, o);
        sq += __shfl_down(sq, o);
    }
    __shared__ float rs[4], rq[4];
    int wid = tid >> 6;
    if ((tid & 63) == 0) { rs[wid] = s; rq[wid] = sq; }
    __syncthreads();
    if (tid == 0) {
        part[(b * 64 + c) * 2]     = rs[0] + rs[1] + rs[2] + rs[3];
        part[(b * 64 + c) * 2 + 1] = rq[0] + rq[1] + rq[2] + rq[3];
    }
}

__global__ void k_bnfinal(const float* __restrict__ part,
                          const float* __restrict__ gamma,
                          const float* __restrict__ beta,
                          float* __restrict__ ss) {
    int c = threadIdx.x;                   // 64 threads
    float s = 0.f, sq = 0.f;
#pragma unroll
    for (int b = 0; b < 8; b++) {
        s += part[(b * 64 + c) * 2];
        sq += part[(b * 64 + c) * 2 + 1];
    }
    const float inv = 1.f / (float)(8 * HW);
    float mean = s * inv;
    float var = sq * inv - mean * mean;
    float scale = gamma[c] * rsqrtf(var + 1e-5f);
    ss[c] = scale;
    ss[64 + c] = beta[c] - mean * scale;
}

// ---------------------------------------------------------------------------
// Kernel 4: conv2 via MFMA — validated verbatim.
// ---------------------------------------------------------------------------
__global__ __launch_bounds__(256) void k_conv2(const float* __restrict__ x,
                                               const float* __restrict__ y,
                                               const float* __restrict__ ss,
                                               const ushort* __restrict__ wb2,
                                               const float* __restrict__ b2,
                                               float* __restrict__ out) {
    int tile = blockIdx.x, b = blockIdx.y;
    int ty0 = (tile / 16) * 8, tx0 = (tile % 16) * 8;
    int tid = threadIdx.x;

    __shared__ uint lz[3600];              // [100 pos][36 dwords] bf16 c-pairs

    for (int idx = tid; idx < 3200; idx += 256) {
        int q = idx / 100, pos = idx % 100;
        int r = pos / 10, col = pos % 10;
        int gy = ty0 + r - 1, gx = tx0 + col - 1;
        uint u = 0;
        if ((unsigned)gy < 128u && (unsigned)gx < 128u) {
            int c0 = q * 2;
            int gi = ((b * 64 + c0) * HW) + gy * 128 + gx;
            float t0 = fmaf(y[gi], ss[c0], ss[64 + c0]);
            float v0 = fmaxf(t0, 0.f) + x[gi];
            float t1 = fmaf(y[gi + HW], ss[c0 + 1], ss[65 + c0]);
            float v1 = fmaxf(t1, 0.f) + x[gi + HW];
            u = (f2bf(v1) << 16) | f2bf(v0);
        }
        lz[pos * 36 + q] = u;
    }
    __syncthreads();

    int lane = tid & 63, pg = tid >> 6;
    int r16 = lane & 15, jg = lane >> 4;
    int p = pg * 16 + r16;
    int pyA = p >> 3, pxA = p & 7;

    f32x4 acc[8];
#pragma unroll
    for (int ot = 0; ot < 8; ot++) {
        float bv = b2[ot * 16 + r16];
        acc[ot] = (f32x4){bv, bv, bv, bv};
    }

#pragma unroll
    for (int t = 0; t < 9; t++) {
        int pos = (pyA + t / 3) * 10 + (pxA + t % 3);
#pragma unroll
        for (int kc = 0; kc < 2; kc++) {
            short8 av = *(const short8*)(lz + pos * 36 + kc * 16 + jg * 4);
            const ushort* wk = wb2 + (t * 2 + kc) * 4096 + lane * 8;
#pragma unroll
            for (int ot = 0; ot < 8; ot++) {
                short8 bv = *(const short8*)(wk + ot * 512);
                acc[ot] = __builtin_amdgcn_mfma_f32_16x16x32_bf16(av, bv, acc[ot], 0, 0, 0);
            }
        }
    }

    // ---- epilogue: direct per-lane vector stores ----
    int p0 = pg * 16 + jg * 4;
    int yy = ty0 + (p0 >> 3), xx = tx0 + (p0 & 7);
#pragma unroll
    for (int ot = 0; ot < 8; ot++) {
        int oc = ot * 16 + r16;
        *(f32x4*)(out + (size_t)(b * 128 + oc) * HW + yy * 128 + xx) = acc[ot];
    }
}

// ---------------------------------------------------------------------------
extern "C" void kernel_launch(void* const* d_in, const int* in_sizes, int n_in,
                              void* d_out, int out_size, void* d_ws, size_t ws_size,
                              hipStream_t stream) {
    const float* x     = (const float*)d_in[0];
    const float* pw    = (const float*)d_in[1];
    const float* pb    = (const float*)d_in[2];
    const float* dw    = (const float*)d_in[3];
    const float* gamma = (const float*)d_in[4];
    const float* beta  = (const float*)d_in[5];
    const float* cw    = (const float*)d_in[6];
    const float* cb    = (const float*)d_in[7];
    float* out = (float*)d_out;
    float* ws  = (float*)d_ws;

    // workspace layout (float offsets)
    float*  wp1  = ws;                      // 10368
    float*  ss   = ws + 10368;              // 128
    float*  part = ws + 10496;              // 1024
    float*  wpd  = ws + 11520;              // 36864 -> ends 48384
    ushort* wb2  = (ushort*)(ws + 48384);   // 73728 sh (36864 f) -> ends 85248
    float*  off  = ws + 85248;              // 2359296 -> ends 2444544
    float*  yb   = ws + 2444544;            // 8388608 -> ends 10833152
    // total: 10833152 floats = 43.3 MB

    k_repack<<<dim3(288), dim3(256), 0, stream>>>(pw, dw, cw, wp1, wpd, wb2);
    k_pconv<<<dim3(64, 8), dim3(256), 0, stream>>>(x, wp1, pb, off);
    k_deform<<<dim3(256, 8), dim3(256), 0, stream>>>(x, off, wpd, yb);
    k_bnpart<<<dim3(64, 8), dim3(256), 0, stream>>>(yb, part);
    k_bnfinal<<<dim3(1), dim3(64), 0, stream>>>(part, gamma, beta, ss);
    k_conv2<<<dim3(256, 8), dim3(256), 0, stream>>>(x, yb, ss, wb2, cb, out);
}

// Round 14
// 350.548 us; speedup vs baseline: 1.1943x; 1.0544x over previous
//
#include <hip/hip_runtime.h>
#include <hip/hip_bf16.h>

// Problem constants
#define BB 8
#define CC 64
#define OO 128
#define HH 128
#define WW 128
#define HW (HH*WW)         // 16384
#define NTAP 9

typedef float f32x4 __attribute__((ext_vector_type(4)));
typedef short short8 __attribute__((ext_vector_type(8)));

__device__ __forceinline__ uint f2bf(float v) {
    uint b = __float_as_uint(v);
    return (b + 0x7FFFu + ((b >> 16) & 1u)) >> 16;   // RNE to bf16
}

__device__ __forceinline__ float sampf(const float* __restrict__ xc, int iy, int ix) {
    // padded-image coords (130x130, zero border of width 1)
    unsigned uy = (unsigned)(iy - 1), ux = (unsigned)(ix - 1);
    return (uy < 128u && ux < 128u) ? xc[uy * 128 + ux] : 0.f;
}

// ---------------------------------------------------------------------------
// Kernel 0: repack weights (validated verbatim).
// ---------------------------------------------------------------------------
__global__ void k_repack(const float* __restrict__ pw, const float* __restrict__ dw,
                         const float* __restrict__ cw,
                         float* __restrict__ wp1, float* __restrict__ wpd,
                         ushort* __restrict__ wb2) {
    int i = blockIdx.x * 256 + threadIdx.x;
    if (i < 10368) {
        int o = i % 18, t = (i / 18) % 9, c = i / 162;
        wp1[i] = pw[(o * 64 + c) * 9 + t];
    }
    if (i < 36864) {
        int o = i % 64, t = (i / 64) % 9, c = i / 576;
        wpd[i] = dw[(o * 64 + c) * 9 + t];
    }
    if (i < 73728) {
        int j = i & 7, lane = (i >> 3) & 63, ot = (i >> 9) & 7;
        int kc = (i >> 12) & 1, t = i >> 13;
        int c = kc * 32 + (lane >> 4) * 8 + j;
        int oc = ot * 16 + (lane & 15);
        wb2[i] = (ushort)f2bf(cw[(oc * 64 + c) * 9 + t]);
    }
}

// ---------------------------------------------------------------------------
// Kernel 1: p_conv — 3x3 conv, 64 -> 18 channels, pad 1 (validated).
// ---------------------------------------------------------------------------
__global__ __launch_bounds__(256) void k_pconv(const float* __restrict__ x,
                                               const float* __restrict__ wp1,
                                               const float* __restrict__ pb,
                                               float* __restrict__ off) {
    int tile = blockIdx.x;
    int b = blockIdx.y;
    int ty0 = (tile / 8) * 16, tx0 = (tile % 8) * 16;
    int tid = threadIdx.x;
    int py = tid / 16, px = tid % 16;
    __shared__ float lx[16][18 * 18];

    float acc[18];
#pragma unroll
    for (int o = 0; o < 18; o++) acc[o] = pb[o];

    for (int cc = 0; cc < 4; cc++) {
        __syncthreads();
        for (int idx = tid; idx < 16 * 324; idx += 256) {
            int c = idx / 324, r = (idx % 324) / 18, col = idx % 18;
            int gy = ty0 + r - 1, gx = tx0 + col - 1;
            float v = 0.f;
            if ((unsigned)gy < 128u && (unsigned)gx < 128u)
                v = x[((b * 64 + cc * 16 + c) * 128 + gy) * 128 + gx];
            lx[c][r * 18 + col] = v;
        }
        __syncthreads();
        for (int c = 0; c < 16; c++) {
#pragma unroll
            for (int t = 0; t < 9; t++) {
                float xv = lx[c][(py + t / 3) * 18 + px + t % 3];
                const float* wr = wp1 + ((cc * 16 + c) * 9 + t) * 18;
#pragma unroll
                for (int o = 0; o < 18; o++) acc[o] = fmaf(xv, wr[o], acc[o]);
            }
        }
    }
    int yy = ty0 + py, xx = tx0 + px;
#pragma unroll
    for (int o = 0; o < 18; o++)
        off[((b * 18 + o) * 128 + yy) * 128 + xx] = acc[o];
}

// ---------------------------------------------------------------------------
// Kernel 2: deformable conv fp32 — bf16 CHANNEL-PAIR packing.
// One random b32 LDS read serves TWO channels (bilinear weights are
// channel-independent); xo packed likewise (proven at 0.031 absmax in
// R3/R5's call-1). Chunk = 8 channels (4 pairs, one per wave), 8 chunks.
// Per-channel LDS instruction count halves vs R13.
// LDS = 2304 + 9216 + 4096 + 9280 = 24896 B -> 6 blocks/CU.
// Phases per chunk (R13-validated order): stage -> SYNC -> gather -> SYNC
// -> contract -> SYNC.
// ---------------------------------------------------------------------------
__global__ __launch_bounds__(256) void k_deform(const float* __restrict__ x,
                                                const float* __restrict__ off,
                                                const float* __restrict__ wpd,
                                                float* __restrict__ y) {
    int tile = blockIdx.x;                 // 0..255
    int b = blockIdx.y;
    int ty0 = (tile / 16) * 8, tx0 = (tile % 16) * 8;
    int tid = threadIdx.x;

    __shared__ uint   mwin[576];           // packed window offsets; 0xFFFFFFFF = fallback
    __shared__ float4 mwt[576];            // bilinear weights (OOB corners zeroed)
    __shared__ uint   xtile[4 * 256];      // [pair][pos] bf16 c-pairs, window = tile +/- 4
    __shared__ uint   xo[4][580];          // [pair][tap*64+px] bf16 c-pairs

    // ---- Stage A: bilinear metadata (R2/R9/R11-proven math) ----
    for (int e = tid; e < 576; e += 256) {
        int n = e >> 6, p = e & 63;
        int py = p >> 3, px = p & 7;
        int yy = ty0 + py, xx = tx0 + px;
        float offh = off[((b * 18 + n) * 128 + yy) * 128 + xx];
        float offw = off[((b * 18 + 9 + n) * 128 + yy) * 128 + xx];
        float ph = (float)(yy + 1) + (float)(n / 3 - 1) + offh;
        float pw = (float)(xx + 1) + (float)(n % 3 - 1) + offw;
        ph = fminf(fmaxf(ph, 0.f), 129.f);
        pw = fminf(fmaxf(pw, 0.f), 129.f);
        float fh = floorf(ph), fw = floorf(pw);
        int lth = (int)fh, ltw = (int)fw;
        int rbh = min(lth + 1, 129), rbw = min(ltw + 1, 129);
        float dh_l = 1.f + (fh - ph);
        float dh_r = 1.f - ((float)rbh - ph);
        float dw_l = 1.f + (fw - pw);
        float dw_r = 1.f - ((float)rbw - pw);
        int uy0 = lth - 1, ux0 = ltw - 1, uy1 = rbh - 1, ux1 = rbw - 1;
        bool iy0 = (unsigned)uy0 < 128u, ix0 = (unsigned)ux0 < 128u;
        bool iy1 = (unsigned)uy1 < 128u, ix1 = (unsigned)ux1 < 128u;
        float w_lt = (iy0 && ix0) ? dh_l * dw_l : 0.f;
        float w_rb = (iy1 && ix1) ? dh_r * dw_r : 0.f;
        float w_lb = (iy0 && ix1) ? dh_l * dw_r : 0.f;
        float w_rt = (iy1 && ix0) ? dh_r * dw_l : 0.f;
        mwt[e] = make_float4(w_lt, w_rb, w_lb, w_rt);
        int wy0 = uy0 - ty0 + 4, wx0 = ux0 - tx0 + 4;
        int wy1 = uy1 - ty0 + 4, wx1 = ux1 - tx0 + 4;
        uint win = 0xFFFFFFFFu;
        if ((unsigned)wy0 < 16u && (unsigned)wx0 < 16u &&
            (unsigned)wy1 < 16u && (unsigned)wx1 < 16u) {
            uint o00 = (uint)(wy0 * 16 + wx0);
            uint o11 = (uint)(wy1 * 16 + wx1);
            uint o01 = (uint)(wy0 * 16 + wx1);
            uint o10 = (uint)(wy1 * 16 + wx0);
            win = o00 | (o11 << 8) | (o01 << 16) | (o10 << 24);
        }
        mwin[e] = win;
    }

    float acc[16] = {};
    int cg = tid >> 6;                     // wave id = channel-PAIR in gather
    int l64 = tid & 63;                    // lane = pixel in contraction
    int cgoff = cg * 256;
    int ob = __builtin_amdgcn_readfirstlane(cg * 16);  // wave's oc base

    // staging coords for this thread (position = tid)
    int sgy = ty0 - 4 + (tid >> 4), sgx = tx0 - 4 + (tid & 15);
    bool sinb = ((unsigned)sgy < 128u && (unsigned)sgx < 128u);
    int spos = sgy * 128 + sgx;

    for (int cc = 0; cc < 8; cc++) {
        // ---- stage 16x16 window, 8 channels packed as 4 bf16-pairs ----
#pragma unroll
        for (int q = 0; q < 4; q++) {
            int c0 = cc * 8 + 2 * q;
            float v0 = 0.f, v1 = 0.f;
            if (sinb) {
                v0 = x[(size_t)(b * 64 + c0) * HW + spos];
                v1 = x[(size_t)(b * 64 + c0 + 1) * HW + spos];
            }
            xtile[q * 256 + tid] = (f2bf(v1) << 16) | f2bf(v0);
        }
        __syncthreads();                   // xtile staged (prev phases closed)
        // ---- gather: 4 random b32 reads serve 2 channels each ----
#pragma unroll 2
        for (int i = 0; i < 9; i++) {
            int e = l64 + 64 * i;
            uint w = mwin[e];
            float4 g = mwt[e];
            float vlo, vhi;
            if (__builtin_expect(w != 0xFFFFFFFFu, 1)) {
                uint u00 = xtile[cgoff + (w & 255u)];
                uint u11 = xtile[cgoff + ((w >> 8) & 255u)];
                uint u01 = xtile[cgoff + ((w >> 16) & 255u)];
                uint u10 = xtile[cgoff + (w >> 24)];
                float a00l = __uint_as_float(u00 << 16), a00h = __uint_as_float(u00 & 0xFFFF0000u);
                float a11l = __uint_as_float(u11 << 16), a11h = __uint_as_float(u11 & 0xFFFF0000u);
                float a01l = __uint_as_float(u01 << 16), a01h = __uint_as_float(u01 & 0xFFFF0000u);
                float a10l = __uint_as_float(u10 << 16), a10h = __uint_as_float(u10 & 0xFFFF0000u);
                vlo = g.x * a00l + g.y * a11l + g.z * a01l + g.w * a10l;
                vhi = g.x * a00h + g.y * a11h + g.z * a01h + g.w * a10h;
            } else {
                // cold fallback: exact R2 global path for both channels
                int n = e >> 6, p = e & 63;
                int yy2 = ty0 + (p >> 3), xx2 = tx0 + (p & 7);
                float offh = off[((b * 18 + n) * 128 + yy2) * 128 + xx2];
                float offw = off[((b * 18 + 9 + n) * 128 + yy2) * 128 + xx2];
                float ph = fminf(fmaxf((float)(yy2 + 1) + (float)(n / 3 - 1) + offh, 0.f), 129.f);
                float pw = fminf(fmaxf((float)(xx2 + 1) + (float)(n % 3 - 1) + offw, 0.f), 129.f);
                int lth = (int)floorf(ph), ltw = (int)floorf(pw);
                int rbh = min(lth + 1, 129), rbw = min(ltw + 1, 129);
                const float* xc0 = x + (size_t)(b * 64 + cc * 8 + 2 * cg) * HW;
                const float* xc1 = xc0 + HW;
                vlo = g.x * sampf(xc0, lth, ltw) + g.y * sampf(xc0, rbh, rbw)
                    + g.z * sampf(xc0, lth, rbw) + g.w * sampf(xc0, rbh, ltw);
                vhi = g.x * sampf(xc1, lth, ltw) + g.y * sampf(xc1, rbh, rbw)
                    + g.z * sampf(xc1, lth, rbw) + g.w * sampf(xc1, rbh, ltw);
            }
            xo[cg][e] = (f2bf(vhi) << 16) | f2bf(vlo);
        }
        __syncthreads();                   // xo ready
        // ---- contraction: one dword read -> 2 channels x 16 oc FMAs ----
        for (int q = 0; q < 4; q++) {
#pragma unroll
            for (int n = 0; n < 9; n++) {
                uint u = xo[q][n * 64 + l64];
                float xlo = __uint_as_float(u << 16);
                float xhi = __uint_as_float(u & 0xFFFF0000u);
                const float* w0 = wpd + (((cc * 8 + 2 * q) * 9 + n) * 64) + ob;
                const float* w1 = w0 + 576;   // next channel's row
#pragma unroll
                for (int j = 0; j < 16; j++) acc[j] = fmaf(xlo, w0[j], acc[j]);
#pragma unroll
                for (int j = 0; j < 16; j++) acc[j] = fmaf(xhi, w1[j], acc[j]);
            }
        }
        __syncthreads();                   // contraction done before next stage
    }

    // ---- epilogue: direct per-lane stores (lane=pixel, wave's 16 oc) ----
    int yy = ty0 + (l64 >> 3), xx = tx0 + (l64 & 7);
#pragma unroll
    for (int j = 0; j < 16; j++)
        y[(size_t)(b * 64 + ob + j) * HW + yy * 128 + xx] = acc[j];
}

// ---------------------------------------------------------------------------
// Kernel 3a/3b: BN statistics, two-stage (validated).
// ---------------------------------------------------------------------------
__global__ __launch_bounds__(256) void k_bnpart(const float* __restrict__ y,
                                                float* __restrict__ part) {
    int c = blockIdx.x, b = blockIdx.y;
    int tid = threadIdx.x;
    const float4* p = (const float4*)(y + (size_t)(b * 64 + c) * HW);
    float s = 0.f, sq = 0.f;
    for (int i = tid; i < HW / 4; i += 256) {
        float4 v = p[i];
        s += v.x + v.y + v.z + v.w;
        sq += v.x * v.x + v.y * v.y + v.z * v.z + v.w * v.w;
    }
#pragma unroll
    for (int o = 32; o > 0; o >>= 1) {
        s += __shfl_down(s, o);
        sq += __shfl_down(sq, o);
    }
    __shared__ float rs[4], rq[4];
    int wid = tid >> 6;
    if ((tid & 63) == 0) { rs[wid] = s; rq[wid] = sq; }
    __syncthreads();
    if (tid == 0) {
        part[(b * 64 + c) * 2]     = rs[0] + rs[1] + rs[2] + rs[3];
        part[(b * 64 + c) * 2 + 1] = rq[0] + rq[1] + rq[2] + rq[3];
    }
}

__global__ void k_bnfinal(const float* __restrict__ part,
                          const float* __restrict__ gamma,
                          const float* __restrict__ beta,
                          float* __restrict__ ss) {
    int c = threadIdx.x;                   // 64 threads
    float s = 0.f, sq = 0.f;
#pragma unroll
    for (int b = 0; b < 8; b++) {
        s += part[(b * 64 + c) * 2];
        sq += part[(b * 64 + c) * 2 + 1];
    }
    const float inv = 1.f / (float)(8 * HW);
    float mean = s * inv;
    float var = sq * inv - mean * mean;
    float scale = gamma[c] * rsqrtf(var + 1e-5f);
    ss[c] = scale;
    ss[64 + c] = beta[c] - mean * scale;
}

// ---------------------------------------------------------------------------
// Kernel 4: conv2 via MFMA — validated verbatim.
// ---------------------------------------------------------------------------
__global__ __launch_bounds__(256) void k_conv2(const float* __restrict__ x,
                                               const float* __restrict__ y,
                                               const float* __restrict__ ss,
                                               const ushort* __restrict__ wb2,
                                               const float* __restrict__ b2,
                                               float* __restrict__ out) {
    int tile = blockIdx.x, b = blockIdx.y;
    int ty0 = (tile / 16) * 8, tx0 = (tile % 16) * 8;
    int tid = threadIdx.x;

    __shared__ uint lz[3600];              // [100 pos][36 dwords] bf16 c-pairs

    for (int idx = tid; idx < 3200; idx += 256) {
        int q = idx / 100, pos = idx % 100;
        int r = pos / 10, col = pos % 10;
        int gy = ty0 + r - 1, gx = tx0 + col - 1;
        uint u = 0;
        if ((unsigned)gy < 128u && (unsigned)gx < 128u) {
            int c0 = q * 2;
            int gi = ((b * 64 + c0) * HW) + gy * 128 + gx;
            float t0 = fmaf(y[gi], ss[c0], ss[64 + c0]);
            float v0 = fmaxf(t0, 0.f) + x[gi];
            float t1 = fmaf(y[gi + HW], ss[c0 + 1], ss[65 + c0]);
            float v1 = fmaxf(t1, 0.f) + x[gi + HW];
            u = (f2bf(v1) << 16) | f2bf(v0);
        }
        lz[pos * 36 + q] = u;
    }
    __syncthreads();

    int lane = tid & 63, pg = tid >> 6;
    int r16 = lane & 15, jg = lane >> 4;
    int p = pg * 16 + r16;
    int pyA = p >> 3, pxA = p & 7;

    f32x4 acc[8];
#pragma unroll
    for (int ot = 0; ot < 8; ot++) {
        float bv = b2[ot * 16 + r16];
        acc[ot] = (f32x4){bv, bv, bv, bv};
    }

#pragma unroll
    for (int t = 0; t < 9; t++) {
        int pos = (pyA + t / 3) * 10 + (pxA + t % 3);
#pragma unroll
        for (int kc = 0; kc < 2; kc++) {
            short8 av = *(const short8*)(lz + pos * 36 + kc * 16 + jg * 4);
            const ushort* wk = wb2 + (t * 2 + kc) * 4096 + lane * 8;
#pragma unroll
            for (int ot = 0; ot < 8; ot++) {
                short8 bv = *(const short8*)(wk + ot * 512);
                acc[ot] = __builtin_amdgcn_mfma_f32_16x16x32_bf16(av, bv, acc[ot], 0, 0, 0);
            }
        }
    }

    // ---- epilogue: direct per-lane vector stores ----
    int p0 = pg * 16 + jg * 4;
    int yy = ty0 + (p0 >> 3), xx = tx0 + (p0 & 7);
#pragma unroll
    for (int ot = 0; ot < 8; ot++) {
        int oc = ot * 16 + r16;
        *(f32x4*)(out + (size_t)(b * 128 + oc) * HW + yy * 128 + xx) = acc[ot];
    }
}

// ---------------------------------------------------------------------------
extern "C" void kernel_launch(void* const* d_in, const int* in_sizes, int n_in,
                              void* d_out, int out_size, void* d_ws, size_t ws_size,
                              hipStream_t stream) {
    const float* x     = (const float*)d_in[0];
    const float* pw    = (const float*)d_in[1];
    const float* pb    = (const float*)d_in[2];
    const float* dw    = (const float*)d_in[3];
    const float* gamma = (const float*)d_in[4];
    const float* beta  = (const float*)d_in[5];
    const float* cw    = (const float*)d_in[6];
    const float* cb    = (const float*)d_in[7];
    float* out = (float*)d_out;
    float* ws  = (float*)d_ws;

    // workspace layout (float offsets)
    float*  wp1  = ws;                      // 10368
    float*  ss   = ws + 10368;              // 128
    float*  part = ws + 10496;              // 1024
    float*  wpd  = ws + 11520;              // 36864 -> ends 48384
    ushort* wb2  = (ushort*)(ws + 48384);   // 73728 sh (36864 f) -> ends 85248
    float*  off  = ws + 85248;              // 2359296 -> ends 2444544
    float*  yb   = ws + 2444544;            // 8388608 -> ends 10833152
    // total: 10833152 floats = 43.3 MB

    k_repack<<<dim3(288), dim3(256), 0, stream>>>(pw, dw, cw, wp1, wpd, wb2);
    k_pconv<<<dim3(64, 8), dim3(256), 0, stream>>>(x, wp1, pb, off);
    k_deform<<<dim3(256, 8), dim3(256), 0, stream>>>(x, off, wpd, yb);
    k_bnpart<<<dim3(64, 8), dim3(256), 0, stream>>>(yb, part);
    k_bnfinal<<<dim3(1), dim3(64), 0, stream>>>(part, gamma, beta, ss);
    k_conv2<<<dim3(256, 8), dim3(256), 0, stream>>>(x, yb, ss, wb2, cb, out);
}